// Round 8
// baseline (383.189 us; speedup 1.0000x reference)
//
#include <hip/hip_runtime.h>
#include <stdint.h>

// Problem constants (from setup_inputs): B=8, H=256, W=256, C=16, HID=128, steps=2
#define BB 8
#define HH 256
#define WW 256
#define CC 16
#define HID 128
#define NPIX (BB*HH*WW)     // 524288
#define MTILE 64            // pixels per block
#define NBLK (NPIX/MTILE)   // 8192
#define DSTRIDE 20          // Dpart row stride in dwords (16 ch + 4 pad)

typedef float v2f __attribute__((ext_vector_type(2)));

static __device__ __forceinline__ v2f pk_fma(v2f a, v2f b, v2f c) {
  // llvm.fma.v2f32 -> v_pk_fma_f32 on gfx90a+ (packed fp32, 2 FMA/lane/inst)
  return __builtin_elementwise_fma(a, b, c);
}

// ---------------- Threefry2x32 (JAX-compatible, 20 rounds) ----------------
// Verified against Random123 KAT: key=(0,0), ctr=(0,0) -> (0x6b200159, 0x99ba4efe).
__host__ __device__ __forceinline__ uint32_t rotl32(uint32_t x, int r) {
  return (x << r) | (x >> (32 - r));
}

__host__ __device__ inline void threefry2x32(uint32_t k0, uint32_t k1,
                                             uint32_t x0, uint32_t x1,
                                             uint32_t& o0, uint32_t& o1) {
  const uint32_t ks2 = k0 ^ k1 ^ 0x1BD11BDAu;
  x0 += k0; x1 += k1;
#define TF_R4(a,b,c,d) \
  x0 += x1; x1 = rotl32(x1,(a)); x1 ^= x0; \
  x0 += x1; x1 = rotl32(x1,(b)); x1 ^= x0; \
  x0 += x1; x1 = rotl32(x1,(c)); x1 ^= x0; \
  x0 += x1; x1 = rotl32(x1,(d)); x1 ^= x0;
  TF_R4(13,15,26,6)   x0 += k1;  x1 += ks2 + 1u;
  TF_R4(17,29,16,24)  x0 += ks2; x1 += k0 + 2u;
  TF_R4(13,15,26,6)   x0 += k0;  x1 += k1 + 3u;
  TF_R4(17,29,16,24)  x0 += k1;  x1 += ks2 + 4u;
  TF_R4(13,15,26,6)   x0 += ks2; x1 += k0 + 5u;
#undef TF_R4
  o0 = x0; o1 = x1;
}

// ---------------- Fused step kernel ----------------
// Block = 256 threads (4 waves), 64-pixel tile. Round-7 structure (GEMM1
// wave-split over hidden w/ scalar W0 loads; GEMM2 partials in-register w/
// scalar W1 loads; cross-wave reduce via 20KB LDS union) + round-8 change:
// GEMM1/GEMM2 inner loops use PACKED FP32 (v_pk_fma_f32) via v2f fma — 2
// FMAs/lane/inst. Accumulator chains remain per-component with identical k/s
// order -> output bitwise identical to rounds 5-7.
__global__ __launch_bounds__(256, 4)
void step_fused(const float* __restrict__ xin,
                const float* __restrict__ W0g,
                const float* __restrict__ b0g,
                const float* __restrict__ W1g,
                float* __restrict__ xn,
                float* __restrict__ alpha_out,
                unsigned char* __restrict__ prelife,
                uint32_t k0, uint32_t k1) {
  __shared__ float Sh[80 * MTILE];   // 20480 B: Ys[80][64], then Dpart[4][64][20]

  const int t   = threadIdx.x;
  const int blk = blockIdx.x;

  // ---------------- perception: 4 channels per thread ----------------
  const int px  = t >> 2;        // 0..63 within tile
  const int c4  = (t & 3) * 4;   // channel quarter: 0,4,8,12
  const int gpx = blk * MTILE + px;
  const int bi  = gpx >> 16;     // H*W = 65536
  const int ij  = gpx & 0xFFFF;
  const int ic  = ij >> 8;
  const int jc  = ij & 0xFF;

  // 3x3 correlation weights (ANGLE=0: w1=dx, w2=dy), /8 pre-applied.
  // XLA conv_general_dilated is cross-correlation (no flip).
  const float DXW[3][3] = {{-0.125f, 0.0f, 0.125f},
                           {-0.25f,  0.0f, 0.25f },
                           {-0.125f, 0.0f, 0.125f}};
  const float DYW[3][3] = {{-0.125f, -0.25f, -0.125f},
                           { 0.0f,    0.0f,   0.0f  },
                           { 0.125f,  0.25f,  0.125f}};
  const float LPW[3][3] = {{0.125f, 0.25f, 0.125f},
                           {0.25f, -1.5f,  0.25f },
                           {0.125f, 0.25f, 0.125f}};
  const float L2W[3][3] = {{0.0f,   0.125f, 0.0f  },
                           {0.125f, -0.5f,  0.125f},
                           {0.0f,   0.125f, 0.0f  }};

  float ctr[4] = {0,0,0,0};
  float adx[4] = {0,0,0,0};
  float ady[4] = {0,0,0,0};
  float alp[4] = {0,0,0,0};
  float al2[4] = {0,0,0,0};
  float amax = 0.0f;

  const float* xb = xin + (size_t)bi * (HH * WW * CC);
#pragma unroll
  for (int di = -1; di <= 1; ++di) {
#pragma unroll
    for (int dj = -1; dj <= 1; ++dj) {
      const int ii = ic + di, jj = jc + dj;
      const bool ok = ((unsigned)ii < (unsigned)HH) && ((unsigned)jj < (unsigned)WW);
      float4 p = make_float4(0.f, 0.f, 0.f, 0.f);
      if (ok) p = *(const float4*)(xb + ((size_t)(ii * WW + jj) * CC + c4));
      const float wdx = DXW[di+1][dj+1], wdy = DYW[di+1][dj+1];
      const float wlp = LPW[di+1][dj+1], wl2 = L2W[di+1][dj+1];
      const float pv[4] = {p.x, p.y, p.z, p.w};
#pragma unroll
      for (int q = 0; q < 4; ++q) {
        if (di == 0 && dj == 0) ctr[q] = pv[q];
        if (wdx != 0.f) adx[q] = fmaf(pv[q], wdx, adx[q]);
        if (wdy != 0.f) ady[q] = fmaf(pv[q], wdy, ady[q]);
        if (wlp != 0.f) alp[q] = fmaf(pv[q], wlp, alp[q]);
        if (wl2 != 0.f) al2[q] = fmaf(pv[q], wl2, al2[q]);
      }
      if (c4 == 0) amax = fmaxf(amax, p.w);   // channel 3 lives in quarter 0
    }
  }
#pragma unroll
  for (int q = 0; q < 4; ++q) {
    Sh[(c4 + q) * MTILE + px]      = ctr[q];
    Sh[(16 + c4 + q) * MTILE + px] = adx[q];
    Sh[(32 + c4 + q) * MTILE + px] = ady[q];
    Sh[(48 + c4 + q) * MTILE + px] = alp[q];
    Sh[(64 + c4 + q) * MTILE + px] = al2[q];
  }
  if (c4 == 0) prelife[gpx] = (amax > 0.1f) ? 1 : 0;

  __syncthreads();

  // ------- GEMM1: h[hid][px] = relu(Y @ W0 + b0), wave-split over hidden ----
  // Packed fp32: acc2[s2] holds hidden units (2*s2, 2*s2+1); component chains
  // keep the exact k order -> bitwise identical to scalar version.
  const int lane = t & 63;
  const int wid  = __builtin_amdgcn_readfirstlane(t >> 6);   // 0..3, uniform
  const float* __restrict__ wslice = W0g + wid * 32;   // W0 row-major [80][128]
  const float* __restrict__ bslice = b0g + wid * 32;

  v2f acc2[16];
  {
    const v2f* __restrict__ b2 = (const v2f*)bslice;   // 128B-aligned
#pragma unroll
    for (int s2 = 0; s2 < 16; ++s2) acc2[s2] = b2[s2]; // scalar loads (uniform)
  }

#pragma unroll 4
  for (int k = 0; k < 80; ++k) {
    const float yk = Sh[k * MTILE + lane];             // ds_read_b32, bank=lane
    v2f y2; y2[0] = yk; y2[1] = yk;
    const v2f* __restrict__ wr2 = (const v2f*)(wslice + k * HID); // wave-uniform
#pragma unroll
    for (int s2 = 0; s2 < 16; ++s2)
      acc2[s2] = pk_fma(wr2[s2], y2, acc2[s2]);        // v_pk_fma_f32, sgpr src
  }

  // ------- GEMM2 partial, in-register: dpart[c] over this wave's 32 hid -----
  v2f dp2[8];
#pragma unroll
  for (int c2 = 0; c2 < 8; ++c2) { dp2[c2][0] = 0.f; dp2[c2][1] = 0.f; }
#pragma unroll 4
  for (int s = 0; s < 32; ++s) {
    const float hr = fmaxf(acc2[s >> 1][s & 1], 0.f);
    v2f h2; h2[0] = hr; h2[1] = hr;
    const v2f* __restrict__ w1r = (const v2f*)(W1g + (wid * 32 + s) * CC); // uniform
#pragma unroll
    for (int c2 = 0; c2 < 8; ++c2)
      dp2[c2] = pk_fma(h2, w1r[c2], dp2[c2]);          // v_pk_fma_f32
  }

  __syncthreads();      // all Ys reads complete before Dpart overwrites union

  // Dpart[wid][px][DSTRIDE]: stride 20 dwords -> b128 writes cover all 32 banks.
  {
    float* drow = Sh + (wid * MTILE + lane) * DSTRIDE;
#pragma unroll
    for (int q = 0; q < 4; ++q)
      *(float4*)&drow[q * 4] = make_float4(dp2[2*q][0], dp2[2*q][1],
                                           dp2[2*q+1][0], dp2[2*q+1][1]);
  }
  __syncthreads();

  // ------- cross-wave reduce + stochastic update + store --------------------
  // Thread t: pixel px (= perception px), channels c4..c4+3 (= perception
  // quarter) -> x values are this thread's own ctr[0..3] registers.
  float4 dsum;
  {
    const float* base = Sh + px * DSTRIDE + c4;
    float4 p0 = *(const float4*)&base[0 * MTILE * DSTRIDE];
    float4 p1 = *(const float4*)&base[1 * MTILE * DSTRIDE];
    float4 p2 = *(const float4*)&base[2 * MTILE * DSTRIDE];
    float4 p3 = *(const float4*)&base[3 * MTILE * DSTRIDE];
    dsum.x = ((p0.x + p1.x) + p2.x) + p3.x;
    dsum.y = ((p0.y + p1.y) + p2.y) + p3.y;
    dsum.z = ((p0.z + p1.z) + p2.z) + p3.z;
    dsum.w = ((p0.w + p1.w) + p2.w) + p3.w;
  }

  // JAX uniform(key,(B,H,W,1)) > 0.5; jax_threefry_partitionable=True:
  // bits[i] = o0 ^ o1 of threefry(key, 0, i).
  uint32_t lo, hi;
  threefry2x32(k0, k1, 0u, (uint32_t)gpx, lo, hi);
  const uint32_t bits = lo ^ hi;
  const float u = __uint_as_float((bits >> 9) | 0x3f800000u) - 1.0f;
  const float fire01 = (u > 0.5f) ? 1.0f : 0.0f;

  const float xv0 = fmaf(dsum.x, fire01, ctr[0]);
  const float xv1 = fmaf(dsum.y, fire01, ctr[1]);
  const float xv2 = fmaf(dsum.z, fire01, ctr[2]);
  const float xv3 = fmaf(dsum.w, fire01, ctr[3]);

  // lane address = 4*t floats -> perfectly coalesced dwordx4 stores
  *(float4*)&xn[(size_t)gpx * CC + c4] = make_float4(xv0, xv1, xv2, xv3);
  if (c4 == 0) alpha_out[gpx] = xv3;   // channel 3
}

// ---------------- Kernel B: life mask ----------------
__global__ __launch_bounds__(256)
void life_mask(const float* __restrict__ xn,
               const float* __restrict__ alpha,
               const unsigned char* __restrict__ prelife,
               float* __restrict__ out) {
  const int idx = blockIdx.x * 256 + threadIdx.x;
  const int b  = idx >> 16;
  const int ij = idx & 0xFFFF;
  const int i  = ij >> 8;
  const int j  = ij & 0xFF;

  const float* ab = alpha + (size_t)b * (HH * WW);
  float amax = 0.0f;  // 0 for OOB is safe vs threshold 0.1
#pragma unroll
  for (int di = -1; di <= 1; ++di) {
    const int ii = i + di;
    if ((unsigned)ii >= (unsigned)HH) continue;
#pragma unroll
    for (int dj = -1; dj <= 1; ++dj) {
      const int jj = j + dj;
      if ((unsigned)jj >= (unsigned)WW) continue;
      amax = fmaxf(amax, ab[(size_t)ii * WW + jj]);
    }
  }
  const bool life = (prelife[idx] != 0) && (amax > 0.1f);

  const float4* src = (const float4*)(xn + (size_t)idx * CC);
  float4* dst = (float4*)(out + (size_t)idx * CC);
  if (life) {
    dst[0] = src[0]; dst[1] = src[1]; dst[2] = src[2]; dst[3] = src[3];
  } else {
    const float4 z = make_float4(0.0f, 0.0f, 0.0f, 0.0f);
    dst[0] = z; dst[1] = z; dst[2] = z; dst[3] = z;
  }
}

// ---------------- Host launcher ----------------
extern "C" void kernel_launch(void* const* d_in, const int* in_sizes, int n_in,
                              void* d_out, int out_size, void* d_ws, size_t ws_size,
                              hipStream_t stream) {
  (void)in_sizes; (void)n_in; (void)out_size; (void)ws_size;
  const float* x  = (const float*)d_in[0];
  const float* W0 = (const float*)d_in[1];
  const float* b0 = (const float*)d_in[2];
  const float* W1 = (const float*)d_in[3];
  float* out = (float*)d_out;

  // Workspace layout: xn state (32 MB) | alpha plane (2 MB) | prelife mask (0.5 MB)
  float* xn = (float*)d_ws;
  float* alpha = xn + (size_t)NPIX * CC;
  unsigned char* mask = (unsigned char*)(alpha + NPIX);

  const int steps = 2;
  for (int s = 0; s < steps; ++s) {
    // folded key = threefry2x32(seed_key=[0,42], [0, step])
    uint32_t fk0, fk1;
    threefry2x32(0u, 42u, 0u, (uint32_t)s, fk0, fk1);
    const float* xin = (s == 0) ? x : out;
    step_fused<<<NBLK, 256, 0, stream>>>(xin, W0, b0, W1, xn, alpha, mask, fk0, fk1);
    life_mask<<<NPIX / 256, 256, 0, stream>>>(xn, alpha, mask, out);
  }
}